// Round 3
// baseline (359.999 us; speedup 1.0000x reference)
//
#include <hip/hip_runtime.h>

// Problem constants
#define N_ROWS 16384   // B*T
#define C_DIM  1024
#define GV     640     // G*V
#define V_DIM  320
#define G_DIM  2
#define D_DIM  256
#define NG     32768   // N_ROWS * G
#define RK_BLOCKS 1024 // row-kernel grid

typedef __attribute__((ext_vector_type(8))) _Float16 half8;
typedef __attribute__((ext_vector_type(4))) _Float16 half4;
typedef __attribute__((ext_vector_type(4))) float float4v;

#define LDS_AS(p) ((__attribute__((address_space(3))) unsigned int*)(p))
#define GLB_AS(p) ((const __attribute__((address_space(1))) unsigned int*)(p))

// ---------------- Split fp32 -> fp16 hi + fp16 lo ----------------
__global__ __launch_bounds__(256) void split_kernel(const float* __restrict__ src,
                                                    _Float16* __restrict__ hi,
                                                    _Float16* __restrict__ lo,
                                                    int n4) {
  const int i = blockIdx.x * 256 + threadIdx.x;
  if (i >= n4) return;
  const float4 v = ((const float4*)src)[i];
  half4 h, l;
  h.x = (_Float16)v.x; l.x = (_Float16)(v.x - (float)h.x);
  h.y = (_Float16)v.y; l.y = (_Float16)(v.y - (float)h.y);
  h.z = (_Float16)v.z; l.z = (_Float16)(v.z - (float)h.z);
  h.w = (_Float16)v.w; l.w = (_Float16)(v.w - (float)h.w);
  ((half4*)hi)[i] = h;
  ((half4*)lo)[i] = l;
}

// ---------------- MFMA GEMM: partial logits = x @ W^T (split fp16, fp32 acc) --------
// 128x128 block tile, BK=32, 4 waves each 64x64, 16x16x32 f16 MFMA, 3 products.
// blockIdx.z picks the K-slice; each z writes its own output buffer.
__global__ __launch_bounds__(256) void gemm_mfma_kernel(
    const _Float16* __restrict__ xh, const _Float16* __restrict__ xl,
    const _Float16* __restrict__ wh, const _Float16* __restrict__ wl,
    float* __restrict__ out0, int ksize) {
  __shared__ _Float16 Ah[128 * 32];
  __shared__ _Float16 Al[128 * 32];
  __shared__ _Float16 Bh[128 * 32];
  __shared__ _Float16 Bl[128 * 32];

  const int tid = threadIdx.x;
  const int lane = tid & 63;
  const int w = tid >> 6;
  const int m0 = blockIdx.y * 128;
  const int n0 = blockIdx.x * 128;
  const int kbase = blockIdx.z * ksize;
  float* out = out0 + (size_t)blockIdx.z * N_ROWS * GV;

  const int srow = lane >> 2;        // 0..15
  const int skoff = (lane & 3) * 8;  // 0,8,16,24 (halves)
  const _Float16* gAh = xh + (size_t)(m0 + w * 32 + srow) * C_DIM + skoff + kbase;
  const _Float16* gAl = xl + (size_t)(m0 + w * 32 + srow) * C_DIM + skoff + kbase;
  const _Float16* gBh = wh + (size_t)(n0 + w * 32 + srow) * C_DIM + skoff + kbase;
  const _Float16* gBl = wl + (size_t)(n0 + w * 32 + srow) * C_DIM + skoff + kbase;
  _Float16* lAh = Ah + (w * 32) * 32;
  _Float16* lAl = Al + (w * 32) * 32;
  _Float16* lBh = Bh + (w * 32) * 32;
  _Float16* lBl = Bl + (w * 32) * 32;
  const size_t rstep = (size_t)16 * C_DIM;

  const int wm = (w & 1) * 64;
  const int wn = (w >> 1) * 64;
  const int frow = lane & 15;
  const int fk = (lane >> 4) * 8;

  float4v acc[4][4];
#pragma unroll
  for (int i = 0; i < 4; ++i)
#pragma unroll
    for (int j = 0; j < 4; ++j) acc[i][j] = (float4v)0.0f;

  for (int k0 = 0; k0 < ksize; k0 += 32) {
    __builtin_amdgcn_global_load_lds(GLB_AS(gAh + k0),         LDS_AS(lAh),            16, 0, 0);
    __builtin_amdgcn_global_load_lds(GLB_AS(gAh + rstep + k0), LDS_AS(lAh + 16 * 32),  16, 0, 0);
    __builtin_amdgcn_global_load_lds(GLB_AS(gAl + k0),         LDS_AS(lAl),            16, 0, 0);
    __builtin_amdgcn_global_load_lds(GLB_AS(gAl + rstep + k0), LDS_AS(lAl + 16 * 32),  16, 0, 0);
    __builtin_amdgcn_global_load_lds(GLB_AS(gBh + k0),         LDS_AS(lBh),            16, 0, 0);
    __builtin_amdgcn_global_load_lds(GLB_AS(gBh + rstep + k0), LDS_AS(lBh + 16 * 32),  16, 0, 0);
    __builtin_amdgcn_global_load_lds(GLB_AS(gBl + k0),         LDS_AS(lBl),            16, 0, 0);
    __builtin_amdgcn_global_load_lds(GLB_AS(gBl + rstep + k0), LDS_AS(lBl + 16 * 32),  16, 0, 0);
    __syncthreads();

    half8 a_h[4], a_l[4];
#pragma unroll
    for (int i = 0; i < 4; ++i) {
      a_h[i] = *(const half8*)&Ah[(wm + i * 16 + frow) * 32 + fk];
      a_l[i] = *(const half8*)&Al[(wm + i * 16 + frow) * 32 + fk];
    }
#pragma unroll
    for (int j = 0; j < 4; ++j) {
      const half8 b_h = *(const half8*)&Bh[(wn + j * 16 + frow) * 32 + fk];
      const half8 b_l = *(const half8*)&Bl[(wn + j * 16 + frow) * 32 + fk];
#pragma unroll
      for (int i = 0; i < 4; ++i) {
        acc[i][j] = __builtin_amdgcn_mfma_f32_16x16x32_f16(a_h[i], b_h, acc[i][j], 0, 0, 0);
        acc[i][j] = __builtin_amdgcn_mfma_f32_16x16x32_f16(a_h[i], b_l, acc[i][j], 0, 0, 0);
        acc[i][j] = __builtin_amdgcn_mfma_f32_16x16x32_f16(a_l[i], b_h, acc[i][j], 0, 0, 0);
      }
    }
    __syncthreads();
  }

  // epilogue: D row=(lane>>4)*4+r, col=lane&15 per 16x16 tile
  const int quad = lane >> 4;
#pragma unroll
  for (int j = 0; j < 4; ++j) {
    const int col = n0 + wn + j * 16 + frow;
#pragma unroll
    for (int i = 0; i < 4; ++i) {
      const int rbase = m0 + wm + i * 16 + quad * 4;
#pragma unroll
      for (int r = 0; r < 4; ++r)
        out[(size_t)(rbase + r) * GV + col] = acc[i][j][r];
    }
  }
}

// ---------------- Fallback fp32 GEMM ----------------
#define BM 64
#define BN 64
#define BK 16
__global__ __launch_bounds__(256) void gemm_logits_kernel(
    const float* __restrict__ A, const float* __restrict__ W,
    float* __restrict__ out) {
  __shared__ float As[BK][BM + 1];
  __shared__ float Bs[BK][BN + 1];
  const int tid = threadIdx.x;
  const int bm0 = blockIdx.y * BM;
  const int bn0 = blockIdx.x * BN;
  const int tx = tid & 15;
  const int ty = tid >> 4;
  const int lr = tid >> 2;
  const int lk = (tid & 3) << 2;

  float acc[4][4] = {};
  const float* Aptr = A + (size_t)(bm0 + lr) * C_DIM + lk;
  const float* Wptr = W + (size_t)(bn0 + lr) * C_DIM + lk;

  for (int k0 = 0; k0 < C_DIM; k0 += BK) {
    float4 a4 = *(const float4*)(Aptr + k0);
    float4 b4 = *(const float4*)(Wptr + k0);
    As[lk + 0][lr] = a4.x; As[lk + 1][lr] = a4.y;
    As[lk + 2][lr] = a4.z; As[lk + 3][lr] = a4.w;
    Bs[lk + 0][lr] = b4.x; Bs[lk + 1][lr] = b4.y;
    Bs[lk + 2][lr] = b4.z; Bs[lk + 3][lr] = b4.w;
    __syncthreads();
#pragma unroll
    for (int kk = 0; kk < BK; ++kk) {
      float av[4], bv[4];
#pragma unroll
      for (int i = 0; i < 4; ++i) av[i] = As[kk][ty * 4 + i];
#pragma unroll
      for (int j = 0; j < 4; ++j) bv[j] = Bs[kk][tx * 4 + j];
#pragma unroll
      for (int i = 0; i < 4; ++i)
#pragma unroll
        for (int j = 0; j < 4; ++j)
          acc[i][j] = fmaf(av[i], bv[j], acc[i][j]);
    }
    __syncthreads();
  }
#pragma unroll
  for (int i = 0; i < 4; ++i) {
    const int m = bm0 + ty * 4 + i;
#pragma unroll
    for (int j = 0; j < 4; ++j) {
      const int v = bn0 + tx * 4 + j;
      out[(size_t)m * GV + v] = acc[i][j];
    }
  }
}

// ---------------- Row kernel: one wave per (n,g) row ----------------
#define ROWS_PER_WAVE 8
#define WAVES_PER_BLOCK 4
#define ROWS_PER_BLOCK (ROWS_PER_WAVE * WAVES_PER_BLOCK)  // 32

__global__ __launch_bounds__(256) void row_kernel(
    const float* __restrict__ l0, const float* __restrict__ l1,  // l1 may be null
    const float* __restrict__ bias,
    const float* __restrict__ gn, const float* __restrict__ cb,
    float* __restrict__ q,
    float* __restrict__ pf, int* __restrict__ pi) {   // per-block partials [grid][GV]
  __shared__ float accL[GV];
  __shared__ int cntL[GV];
  const int tid = threadIdx.x;
  for (int e = tid; e < GV; e += 256) { accL[e] = 0.0f; cntL[e] = 0; }
  __syncthreads();

  const int lane = tid & 63;
  const int w = tid >> 6;
  const int r0 = blockIdx.x * ROWS_PER_BLOCK + w * ROWS_PER_WAVE;

  float bb[G_DIM][5];
#pragma unroll
  for (int g = 0; g < G_DIM; ++g)
#pragma unroll
    for (int j = 0; j < 5; ++j) bb[g][j] = bias[g * V_DIM + lane + 64 * j];

  float pacc[G_DIM][5] = {};

#pragma unroll
  for (int i = 0; i < ROWS_PER_WAVE; ++i) {
    const int g = i & 1;
    const int r = r0 + i;
    const int n = r >> 1;
    const size_t base = (size_t)n * GV + g * V_DIM;
    const float* gp = gn + (size_t)r * V_DIM;

    float l[5], t[5];
#pragma unroll
    for (int j = 0; j < 5; ++j) {
      const int v = lane + 64 * j;
      float lv = l0[base + v];
      if (l1) lv += l1[base + v];
      lv += bb[g][j];
      l[j] = lv;
      t[j] = (lv + gp[v]) * 0.5f;
    }

    float m = l[0]; int mi = lane;
#pragma unroll
    for (int j = 1; j < 5; ++j) {
      const int v = lane + 64 * j;
      if (l[j] > m) { m = l[j]; mi = v; }
    }
#pragma unroll
    for (int off = 32; off > 0; off >>= 1) {
      const float om = __shfl_xor(m, off, 64);
      const int omi = __shfl_xor(mi, off, 64);
      if (om > m || (om == m && omi < mi)) { m = om; mi = omi; }
    }
    if (lane == 0) atomicAdd(&cntL[g * V_DIM + mi], 1);

    float e[5], s = 0.0f;
#pragma unroll
    for (int j = 0; j < 5; ++j) { e[j] = expf(l[j] - m); s += e[j]; }
#pragma unroll
    for (int off = 32; off > 0; off >>= 1) s += __shfl_xor(s, off, 64);
    const float inv = 1.0f / s;
#pragma unroll
    for (int j = 0; j < 5; ++j) pacc[g][j] += e[j] * inv;

    float tm = t[0]; int ti = lane;
#pragma unroll
    for (int j = 1; j < 5; ++j) {
      const int v = lane + 64 * j;
      if (t[j] > tm) { tm = t[j]; ti = v; }
    }
#pragma unroll
    for (int off = 32; off > 0; off >>= 1) {
      const float om = __shfl_xor(tm, off, 64);
      const int omi = __shfl_xor(ti, off, 64);
      if (om > tm || (om == tm && omi < ti)) { tm = om; ti = omi; }
    }
    float ts = 0.0f;
#pragma unroll
    for (int j = 0; j < 5; ++j) ts += expf(t[j] - tm);
#pragma unroll
    for (int off = 32; off > 0; off >>= 1) ts += __shfl_xor(ts, off, 64);
    const float sv = 1.0f / ts;
    const float yv = (1.0f + sv) - sv;

    const float4* cbp = (const float4*)(cb + ((size_t)(g * V_DIM + ti)) * D_DIM);
    const float4 c4 = cbp[lane];
    float4 o4;
    o4.x = yv * c4.x; o4.y = yv * c4.y; o4.z = yv * c4.z; o4.w = yv * c4.w;
    ((float4*)q)[(size_t)n * 128 + g * 64 + lane] = o4;
  }

#pragma unroll
  for (int g2 = 0; g2 < G_DIM; ++g2)
#pragma unroll
    for (int j = 0; j < 5; ++j)
      atomicAdd(&accL[g2 * V_DIM + lane + 64 * j], pacc[g2][j]);
  __syncthreads();

  const size_t pb = (size_t)blockIdx.x * GV;
  for (int e2 = tid; e2 < GV; e2 += 256) {
    pf[pb + e2] = accL[e2];
    pi[pb + e2] = cntL[e2];
  }
}

// ---------------- Stage-1 reduce: 1024 partial rows -> 64 ----------------
__global__ __launch_bounds__(256) void reduce_kernel(
    const float* __restrict__ pf, const int* __restrict__ pi,
    float* __restrict__ mf, int* __restrict__ mi) {
  const int b = blockIdx.x;  // 0..63, covers partial rows [b*16, b*16+16)
  for (int e = threadIdx.x; e < GV; e += 256) {
    float sf = 0.0f; int si = 0;
#pragma unroll
    for (int r = 0; r < 16; ++r) {
      sf += pf[(size_t)(b * 16 + r) * GV + e];
      si += pi[(size_t)(b * 16 + r) * GV + e];
    }
    mf[(size_t)b * GV + e] = sf;
    mi[(size_t)b * GV + e] = si;
  }
}

// ---------------- Finalize: sum 64 mids, entropies, outputs ----------------
__global__ __launch_bounds__(256) void finalize_kernel(
    const float* __restrict__ mf, const int* __restrict__ mi,
    float* __restrict__ out3) {
  __shared__ float sA[G_DIM];
  __shared__ float sC[G_DIM];
  if (threadIdx.x < G_DIM) { sA[threadIdx.x] = 0.0f; sC[threadIdx.x] = 0.0f; }
  __syncthreads();

  for (int e = threadIdx.x; e < GV; e += 256) {
    float f = 0.0f; int c = 0;
#pragma unroll
    for (int b = 0; b < 64; ++b) {
      f += mf[(size_t)b * GV + e];
      c += mi[(size_t)b * GV + e];
    }
    const int g = e / V_DIM;
    const float pa = f * (1.0f / 16384.0f);
    const float ph = (float)c * (1.0f / 16384.0f);
    atomicAdd(&sA[g], pa * logf(pa + 1e-7f));
    atomicAdd(&sC[g], ph * logf(ph + 1e-7f));
  }
  __syncthreads();
  if (threadIdx.x == 0) {
    const float code_p = expf(-sC[0]) + expf(-sC[1]);
    const float prob_p = expf(-sA[0]) + expf(-sA[1]);
    out3[0] = code_p;
    out3[1] = prob_p;
    out3[2] = ((float)GV - prob_p) / (float)GV;
  }
}

extern "C" void kernel_launch(void* const* d_in, const int* in_sizes, int n_in,
                              void* d_out, int out_size, void* d_ws, size_t ws_size,
                              hipStream_t stream) {
  const float* x  = (const float*)d_in[0];
  const float* W  = (const float*)d_in[1];
  const float* b  = (const float*)d_in[2];
  const float* cb = (const float*)d_in[3];
  const float* gn = (const float*)d_in[4];
  float* out = (float*)d_out;

  char* ws = (char*)d_ws;
  const size_t LOGITS_B = (size_t)N_ROWS * GV * 4;   // 41,943,040
  const size_t XH_B     = (size_t)N_ROWS * C_DIM * 2; // 33,554,432
  const size_t WH_B     = (size_t)GV * C_DIM * 2;     // 1,310,720
  const size_t PF_B     = (size_t)RK_BLOCKS * GV * 4; // 2,621,440
  const size_t MF_B     = (size_t)64 * GV * 4;        // 163,840

  float* logits0 = (float*)ws;

  // Tier A: split-K=2 MFMA (needs 2 logits buffers + fp16 copies)
  const size_t tierA = 2 * LOGITS_B + 2 * XH_B + 2 * WH_B;  // ~151 MB
  // Tier B: single-K MFMA (R2 layout)
  const size_t tierB = LOGITS_B + 2 * XH_B + 2 * WH_B;      // ~110 MB
  // Tier C: fp32 fallback
  const size_t tierC = LOGITS_B + 2 * (PF_B + MF_B);        // ~48 MB

  float* l1 = nullptr;
  float *pf, *mf; int *pi, *mi;

  if (ws_size >= tierA) {
    float* logits1 = (float*)(ws + LOGITS_B);
    _Float16* xh = (_Float16*)(ws + 2 * LOGITS_B);
    _Float16* xl = (_Float16*)(ws + 2 * LOGITS_B + XH_B);
    _Float16* wh = (_Float16*)(ws + 2 * LOGITS_B + 2 * XH_B);
    _Float16* wl = (_Float16*)(ws + 2 * LOGITS_B + 2 * XH_B + WH_B);
    // partials alias the xh/xl region (dead after GEMM completes)
    pf = (float*)(ws + 2 * LOGITS_B);
    pi = (int*)  (ws + 2 * LOGITS_B + PF_B);
    mf = (float*)(ws + 2 * LOGITS_B + 2 * PF_B);
    mi = (int*)  (ws + 2 * LOGITS_B + 2 * PF_B + MF_B);
    l1 = logits1;

    split_kernel<<<(N_ROWS * C_DIM / 4 + 255) / 256, 256, 0, stream>>>(x, xh, xl, N_ROWS * C_DIM / 4);
    split_kernel<<<(GV * C_DIM / 4 + 255) / 256, 256, 0, stream>>>(W, wh, wl, GV * C_DIM / 4);
    dim3 ggrid(GV / 128, N_ROWS / 128, 2);  // (5, 128, 2) = 1280 blocks
    gemm_mfma_kernel<<<ggrid, 256, 0, stream>>>(xh, xl, wh, wl, logits0, 512);
  } else if (ws_size >= tierB) {
    _Float16* xh = (_Float16*)(ws + LOGITS_B);
    _Float16* xl = (_Float16*)(ws + LOGITS_B + XH_B);
    _Float16* wh = (_Float16*)(ws + LOGITS_B + 2 * XH_B);
    _Float16* wl = (_Float16*)(ws + LOGITS_B + 2 * XH_B + WH_B);
    pf = (float*)(ws + LOGITS_B);
    pi = (int*)  (ws + LOGITS_B + PF_B);
    mf = (float*)(ws + LOGITS_B + 2 * PF_B);
    mi = (int*)  (ws + LOGITS_B + 2 * PF_B + MF_B);

    split_kernel<<<(N_ROWS * C_DIM / 4 + 255) / 256, 256, 0, stream>>>(x, xh, xl, N_ROWS * C_DIM / 4);
    split_kernel<<<(GV * C_DIM / 4 + 255) / 256, 256, 0, stream>>>(W, wh, wl, GV * C_DIM / 4);
    dim3 ggrid(GV / 128, N_ROWS / 128, 1);
    gemm_mfma_kernel<<<ggrid, 256, 0, stream>>>(xh, xl, wh, wl, logits0, C_DIM);
  } else {
    pf = (float*)(ws + LOGITS_B);
    pi = (int*)  (ws + LOGITS_B + PF_B);
    mf = (float*)(ws + LOGITS_B + 2 * PF_B);
    mi = (int*)  (ws + LOGITS_B + 2 * PF_B + MF_B);
    dim3 ggrid(GV / BN, N_ROWS / BM);
    gemm_logits_kernel<<<ggrid, 256, 0, stream>>>(x, W, logits0);
  }

  row_kernel<<<RK_BLOCKS, 256, 0, stream>>>(logits0, l1, b, gn, cb, out, pf, pi);
  reduce_kernel<<<64, 256, 0, stream>>>(pf, pi, mf, mi);
  finalize_kernel<<<1, 256, 0, stream>>>(mf, mi, out + (size_t)N_ROWS * 512);
}

// Round 4
// 306.233 us; speedup vs baseline: 1.1756x; 1.1756x over previous
//
#include <hip/hip_runtime.h>

// Problem constants
#define N_ROWS 16384   // B*T
#define C_DIM  1024
#define GV     640     // G*V
#define V_DIM  320
#define G_DIM  2
#define D_DIM  256
#define MROWS  32      // rows per fused block
#define FBLKS  (N_ROWS / MROWS)  // 512

typedef __attribute__((ext_vector_type(8))) _Float16 half8;
typedef __attribute__((ext_vector_type(4))) _Float16 half4;
typedef __attribute__((ext_vector_type(2))) _Float16 half2v;
typedef __attribute__((ext_vector_type(4))) float float4v;

#define LDS_AS(p) ((__attribute__((address_space(3))) unsigned int*)(p))
#define GLB_AS(p) ((const __attribute__((address_space(1))) unsigned int*)(p))

// ---------------- W -> fp16 hi (lo term dropped; 2-product split) ----------------
__global__ __launch_bounds__(256) void wsplit_kernel(const float* __restrict__ src,
                                                     _Float16* __restrict__ hi, int n4) {
  const int i = blockIdx.x * 256 + threadIdx.x;
  if (i >= n4) return;
  const float4 v = ((const float4*)src)[i];
  half4 h;
  h.x = (_Float16)v.x; h.y = (_Float16)v.y;
  h.z = (_Float16)v.z; h.w = (_Float16)v.w;
  ((half4*)hi)[i] = h;
}

// ---------------- Fused: GEMM (M=32 x N=640 per block) + row ops ----------------
// Wave w (of 8) owns cols [80w, 80w+80) as 2x5 16x16 tiles over all 32 rows.
// logits = xh@Wh^T + xl@Wh^T (fp32 acc) + bias. Epilogue per group g: owning
// waves dump rows to LDS; all waves run row ops (argmax/softmax/gumbel/q).
__global__ __launch_bounds__(512, 4) void fused_kernel(
    const float* __restrict__ x,      // [N_ROWS, C_DIM] fp32
    const _Float16* __restrict__ wh,  // [GV, C_DIM] fp16 hi
    const float* __restrict__ bias,   // [GV]
    const float* __restrict__ gn,     // [2*N_ROWS, V_DIM]
    const float* __restrict__ cb,     // [GV, D_DIM]
    float* __restrict__ q,            // [N_ROWS, 512]
    float* __restrict__ pf,           // [FBLKS, GV] per-block softmax partials
    int* __restrict__ pi) {           // [FBLKS, GV] per-block argmax counts
  __shared__ __align__(16) char smemU[45056];
  _Float16* AhL = (_Float16*)smemU;            // [0, 2048)   32x32 halves
  _Float16* AlL = (_Float16*)(smemU + 2048);   // [2048, 4096)
  _Float16* BhL = (_Float16*)(smemU + 4096);   // [4096, 45056) 640x32 halves
  float* Ldump  = (float*)smemU;               // [0, 41088) 32 x 321 (epilogue reuse)
  __shared__ float accL[GV];
  __shared__ int   cntL[GV];

  const int tid = threadIdx.x;
  const int lane = tid & 63;
  const int w = tid >> 6;          // wave 0..7
  const int m0 = blockIdx.x * MROWS;
  const int frow = lane & 15;
  const int fk = (lane >> 4) * 8;
  const int quad = lane >> 4;

  for (int e = tid; e < GV; e += 512) { accL[e] = 0.0f; cntL[e] = 0; }

  // A-staging mapping: thread -> (row, k-pair) of the 32x32 fp32 tile
  const int ar = tid >> 4;          // 0..31
  const int ak = (tid & 15) * 2;    // 0,2,..,30
  const float* xp = x + (size_t)(m0 + ar) * C_DIM + ak;

  float4v acc[2][5];
#pragma unroll
  for (int i = 0; i < 2; ++i)
#pragma unroll
    for (int j = 0; j < 5; ++j) acc[i][j] = (float4v)0.0f;

  for (int k0 = 0; k0 < C_DIM; k0 += 32) {
    // B staging: 640x32 halves = 40960 B, 5 x 16 B per thread, async to LDS
#pragma unroll
    for (int s = 0; s < 5; ++s) {
      const int c = s * 512 + tid;       // chunk 0..2559
      const int bn = c >> 2;             // W row 0..639
      const int bk = (c & 3) * 8;        // k offset (halves)
      __builtin_amdgcn_global_load_lds(GLB_AS(wh + (size_t)bn * C_DIM + k0 + bk),
                                       LDS_AS(BhL + c * 8), 16, 0, 0);
    }
    // A staging: fp32 load -> split hi/lo in-register -> LDS
    const float2 a2 = *(const float2*)(xp + k0);
    const _Float16 h0 = (_Float16)a2.x, h1 = (_Float16)a2.y;
    half2v hv, lv;
    hv.x = h0; hv.y = h1;
    lv.x = (_Float16)(a2.x - (float)h0);
    lv.y = (_Float16)(a2.y - (float)h1);
    *(half2v*)&AhL[ar * 32 + ak] = hv;
    *(half2v*)&AlL[ar * 32 + ak] = lv;
    __syncthreads();

    half8 ah[2], al[2];
#pragma unroll
    for (int i = 0; i < 2; ++i) {
      ah[i] = *(const half8*)&AhL[(16 * i + frow) * 32 + fk];
      al[i] = *(const half8*)&AlL[(16 * i + frow) * 32 + fk];
    }
#pragma unroll
    for (int j = 0; j < 5; ++j) {
      const half8 bh = *(const half8*)&BhL[(80 * w + 16 * j + frow) * 32 + fk];
#pragma unroll
      for (int i = 0; i < 2; ++i) {
        acc[i][j] = __builtin_amdgcn_mfma_f32_16x16x32_f16(ah[i], bh, acc[i][j], 0, 0, 0);
        acc[i][j] = __builtin_amdgcn_mfma_f32_16x16x32_f16(al[i], bh, acc[i][j], 0, 0, 0);
      }
    }
    __syncthreads();
  }

  // bias for this wave's cols
  float bw[5];
#pragma unroll
  for (int j = 0; j < 5; ++j) bw[j] = bias[80 * w + 16 * j + frow];

  // -------- epilogue: two group phases --------
#pragma unroll
  for (int g = 0; g < G_DIM; ++g) {
    __syncthreads();  // staging/prev-phase LDS dead
    if ((w >> 2) == g) {
      const int cg0 = 80 * (w & 3) + frow;  // col within group
#pragma unroll
      for (int i = 0; i < 2; ++i)
#pragma unroll
        for (int j = 0; j < 5; ++j)
#pragma unroll
          for (int r = 0; r < 4; ++r)
            Ldump[(16 * i + 4 * quad + r) * 321 + cg0 + 16 * j] = acc[i][j][r] + bw[j];
    }
    __syncthreads();

    float pacc5[5] = {0.0f, 0.0f, 0.0f, 0.0f, 0.0f};
#pragma unroll
    for (int rr = 0; rr < 4; ++rr) {
      const int row = w * 4 + rr;     // 0..31
      const int n = m0 + row;
      const float* gp = gn + (size_t)(2 * n + g) * V_DIM;

      float l[5], t[5];
#pragma unroll
      for (int j = 0; j < 5; ++j) {
        l[j] = Ldump[row * 321 + lane + 64 * j];
        t[j] = (l[j] + gp[lane + 64 * j]) * 0.5f;
      }

      // argmax of l (first index on ties)
      float m = l[0]; int mi = lane;
#pragma unroll
      for (int j = 1; j < 5; ++j) {
        const int v = lane + 64 * j;
        if (l[j] > m) { m = l[j]; mi = v; }
      }
#pragma unroll
      for (int off = 32; off > 0; off >>= 1) {
        const float om = __shfl_xor(m, off, 64);
        const int omi = __shfl_xor(mi, off, 64);
        if (om > m || (om == m && omi < mi)) { m = om; mi = omi; }
      }
      if (lane == 0) atomicAdd(&cntL[g * V_DIM + mi], 1);

      // softmax of l
      float e[5], s = 0.0f;
#pragma unroll
      for (int j = 0; j < 5; ++j) { e[j] = expf(l[j] - m); s += e[j]; }
#pragma unroll
      for (int off = 32; off > 0; off >>= 1) s += __shfl_xor(s, off, 64);
      const float inv = 1.0f / s;
#pragma unroll
      for (int j = 0; j < 5; ++j) pacc5[j] += e[j] * inv;

      // gumbel path
      float tm = t[0]; int ti = lane;
#pragma unroll
      for (int j = 1; j < 5; ++j) {
        const int v = lane + 64 * j;
        if (t[j] > tm) { tm = t[j]; ti = v; }
      }
#pragma unroll
      for (int off = 32; off > 0; off >>= 1) {
        const float om = __shfl_xor(tm, off, 64);
        const int omi = __shfl_xor(ti, off, 64);
        if (om > tm || (om == tm && omi < ti)) { tm = om; ti = omi; }
      }
      float ts = 0.0f;
#pragma unroll
      for (int j = 0; j < 5; ++j) ts += expf(t[j] - tm);
#pragma unroll
      for (int off = 32; off > 0; off >>= 1) ts += __shfl_xor(ts, off, 64);
      const float sv = 1.0f / ts;
      const float yv = (1.0f + sv) - sv;  // straight-through value at argmax

      // q row write: 64 lanes x float4
      const float4 c4 = ((const float4*)(cb + ((size_t)(g * V_DIM + ti)) * D_DIM))[lane];
      float4 o4;
      o4.x = yv * c4.x; o4.y = yv * c4.y; o4.z = yv * c4.z; o4.w = yv * c4.w;
      ((float4*)q)[(size_t)n * 128 + g * 64 + lane] = o4;
    }
#pragma unroll
    for (int j = 0; j < 5; ++j)
      atomicAdd(&accL[g * V_DIM + lane + 64 * j], pacc5[j]);
  }

  __syncthreads();
  const size_t pb = (size_t)blockIdx.x * GV;
  for (int e = tid; e < GV; e += 512) {
    pf[pb + e] = accL[e];
    pi[pb + e] = cntL[e];
  }
}

// ---------------- Stage-1 reduce: 512 partial rows -> 64 ----------------
__global__ __launch_bounds__(256) void reduce_kernel(
    const float* __restrict__ pf, const int* __restrict__ pi,
    float* __restrict__ mf, int* __restrict__ mi) {
  const int b = blockIdx.x;  // 0..63, covers partial rows [b*8, b*8+8)
  for (int e = threadIdx.x; e < GV; e += 256) {
    float sf = 0.0f; int si = 0;
#pragma unroll
    for (int r = 0; r < 8; ++r) {
      sf += pf[(size_t)(b * 8 + r) * GV + e];
      si += pi[(size_t)(b * 8 + r) * GV + e];
    }
    mf[(size_t)b * GV + e] = sf;
    mi[(size_t)b * GV + e] = si;
  }
}

// ---------------- Finalize: sum 64 mids, entropies, outputs ----------------
__global__ __launch_bounds__(256) void finalize_kernel(
    const float* __restrict__ mf, const int* __restrict__ mi,
    float* __restrict__ out3) {
  __shared__ float sA[G_DIM];
  __shared__ float sC[G_DIM];
  if (threadIdx.x < G_DIM) { sA[threadIdx.x] = 0.0f; sC[threadIdx.x] = 0.0f; }
  __syncthreads();

  for (int e = threadIdx.x; e < GV; e += 256) {
    float f = 0.0f; int c = 0;
#pragma unroll
    for (int b = 0; b < 64; ++b) {
      f += mf[(size_t)b * GV + e];
      c += mi[(size_t)b * GV + e];
    }
    const int g = e / V_DIM;
    const float pa = f * (1.0f / 16384.0f);
    const float ph = (float)c * (1.0f / 16384.0f);
    atomicAdd(&sA[g], pa * logf(pa + 1e-7f));
    atomicAdd(&sC[g], ph * logf(ph + 1e-7f));
  }
  __syncthreads();
  if (threadIdx.x == 0) {
    const float code_p = expf(-sC[0]) + expf(-sC[1]);
    const float prob_p = expf(-sA[0]) + expf(-sA[1]);
    out3[0] = code_p;
    out3[1] = prob_p;
    out3[2] = ((float)GV - prob_p) / (float)GV;
  }
}

extern "C" void kernel_launch(void* const* d_in, const int* in_sizes, int n_in,
                              void* d_out, int out_size, void* d_ws, size_t ws_size,
                              hipStream_t stream) {
  const float* x  = (const float*)d_in[0];  // [8,2048,1024]
  const float* W  = (const float*)d_in[1];  // [640,1024]
  const float* b  = (const float*)d_in[2];  // [640]
  const float* cb = (const float*)d_in[3];  // [1,640,256]
  const float* gn = (const float*)d_in[4];  // [32768,320]
  float* out = (float*)d_out;               // q [16384*512] + 3 scalars

  char* ws = (char*)d_ws;
  _Float16* wh = (_Float16*)ws;                    // 1,310,720 B
  float* pf = (float*)(ws + 1310720);              // 512*640*4 = 1,310,720 B
  int*   pi = (int*)  (ws + 2621440);              // 1,310,720 B
  float* mf = (float*)(ws + 3932160);              // 64*640*4 = 163,840 B
  int*   mi = (int*)  (ws + 4096000);              // 163,840 B
  // total ~4.26 MB — well under workspace

  wsplit_kernel<<<(GV * C_DIM / 4 + 255) / 256, 256, 0, stream>>>(W, wh, GV * C_DIM / 4);

  fused_kernel<<<FBLKS, 512, 0, stream>>>(x, wh, b, gn, cb, out, pf, pi);

  reduce_kernel<<<64, 256, 0, stream>>>(pf, pi, mf, mi);
  finalize_kernel<<<1, 256, 0, stream>>>(mf, mi, out + (size_t)N_ROWS * 512);
}

// Round 5
// 275.957 us; speedup vs baseline: 1.3046x; 1.1097x over previous
//
#include <hip/hip_runtime.h>

// Problem constants
#define N_ROWS 16384   // B*T
#define C_DIM  1024
#define GV     640     // G*V
#define V_DIM  320
#define G_DIM  2
#define D_DIM  256
#define MROWS  32      // rows per fused block
#define FBLKS  (N_ROWS / MROWS)  // 512
#define NBUCKET 64

typedef __attribute__((ext_vector_type(8))) _Float16 half8;
typedef __attribute__((ext_vector_type(2))) _Float16 half2v;
typedef __attribute__((ext_vector_type(4))) float float4v;

#define LDS_AS(p) ((__attribute__((address_space(3))) unsigned int*)(p))
#define GLB_AS(p) ((const __attribute__((address_space(1))) unsigned int*)(p))

// ---------------- W -> fp16 hi, pre-swizzled into 16B-chunk-transposed layout ----
// whT[((kb*4 + c)*640 + n)*8 + h] = (half)W[n][kb*32 + c*8 + h]
// so per-K-iter staging is linear AND the resulting LDS layout [c][n] gives
// conflict-free b128 fragment reads (chunk index distinct mod 8 per 8-lane phase).
__global__ __launch_bounds__(256) void wsplit_kernel(const float* __restrict__ src,
                                                     _Float16* __restrict__ dst) {
  const int t = blockIdx.x * 256 + threadIdx.x;  // 0..81919
  const int n = t % GV;
  const int cc = t / GV;       // 0..127 ; k = cc*8
  const int k = cc * 8;
  const float4 v0 = *(const float4*)(src + (size_t)n * C_DIM + k);
  const float4 v1 = *(const float4*)(src + (size_t)n * C_DIM + k + 4);
  half8 h;
  h[0] = (_Float16)v0.x; h[1] = (_Float16)v0.y; h[2] = (_Float16)v0.z; h[3] = (_Float16)v0.w;
  h[4] = (_Float16)v1.x; h[5] = (_Float16)v1.y; h[6] = (_Float16)v1.z; h[7] = (_Float16)v1.w;
  *(half8*)(dst + (size_t)t * 8) = h;
}

// ---------------- Fused: GEMM (M=32 x N=640 per block) + row ops ----------------
__global__ __launch_bounds__(512, 4) void fused_kernel(
    const float* __restrict__ x,       // [N_ROWS, C_DIM] fp32
    const _Float16* __restrict__ whT,  // swizzled fp16 hi of W
    const float* __restrict__ bias,    // [GV]
    const float* __restrict__ gn,      // [2*N_ROWS, V_DIM]
    const float* __restrict__ cb,      // [GV, D_DIM]
    float* __restrict__ q,             // [N_ROWS, 512]
    float* __restrict__ mf,            // [NBUCKET, GV] atomic softmax partials (pre-zeroed)
    int* __restrict__ mi) {            // [NBUCKET, GV] atomic argmax counts (pre-zeroed)
  __shared__ __align__(16) char smemU[45056];
  _Float16* AhL = (_Float16*)smemU;            // [0,2048)    A-hi  [c][row] chunks
  _Float16* AlL = (_Float16*)(smemU + 2048);   // [2048,4096) A-lo
  _Float16* BhL = (_Float16*)(smemU + 4096);   // [4096,45056) B [c][n] chunks
  float* Ldump  = (float*)smemU;               // epilogue reuse: 32 x 321 floats
  __shared__ float accL[GV];
  __shared__ int   cntL[GV];

  const int tid = threadIdx.x;
  const int lane = tid & 63;
  const int w = tid >> 6;          // wave 0..7
  const int m0 = blockIdx.x * MROWS;
  const int frow = lane & 15;
  const int quad = lane >> 4;

  for (int e = tid; e < GV; e += 512) { accL[e] = 0.0f; cntL[e] = 0; }

  // A staging map: thread -> (row ar, k-pair ak) of 32x32 fp32 tile
  const int ar = tid >> 4;           // 0..31
  const int ak = (tid & 15) * 2;     // 0..30 even
  const int ac = ak >> 3;            // chunk 0..3
  const int ah_off = ak & 7;         // within-chunk half offset (even)
  const float* xp = x + (size_t)(m0 + ar) * C_DIM + ak;
  float2 a2 = *(const float2*)xp;    // prefetch k0=0

  float4v acc[2][5];
#pragma unroll
  for (int i = 0; i < 2; ++i)
#pragma unroll
    for (int j = 0; j < 5; ++j) acc[i][j] = (float4v)0.0f;

  for (int k0 = 0; k0 < C_DIM; k0 += 32) {
    // B staging: 2560 chunks x 16B, lane-linear both sides
    const _Float16* bsrc = whT + (size_t)(k0 >> 5) * 2560 * 8;
#pragma unroll
    for (int s = 0; s < 5; ++s) {
      const int c = s * 512 + tid;
      __builtin_amdgcn_global_load_lds(GLB_AS(bsrc + (size_t)c * 8),
                                       LDS_AS(BhL + c * 8), 16, 0, 0);
    }
    // A: in-register split of prefetched fp32, store to [c][row] layout
    const _Float16 h0 = (_Float16)a2.x, h1 = (_Float16)a2.y;
    half2v hv, lv;
    hv.x = h0; hv.y = h1;
    lv.x = (_Float16)(a2.x - (float)h0);
    lv.y = (_Float16)(a2.y - (float)h1);
    *(half2v*)&AhL[(ac * 32 + ar) * 8 + ah_off] = hv;
    *(half2v*)&AlL[(ac * 32 + ar) * 8 + ah_off] = lv;
    if (k0 + 32 < C_DIM) a2 = *(const float2*)(xp + k0 + 32);  // rides the vmcnt drain
    __syncthreads();

    half8 ah[2], al[2];
#pragma unroll
    for (int i = 0; i < 2; ++i) {
      ah[i] = *(const half8*)&AhL[(quad * 32 + 16 * i + frow) * 8];
      al[i] = *(const half8*)&AlL[(quad * 32 + 16 * i + frow) * 8];
    }
#pragma unroll
    for (int j = 0; j < 5; ++j) {
      const half8 bh = *(const half8*)&BhL[(quad * 640 + 80 * w + 16 * j + frow) * 8];
#pragma unroll
      for (int i = 0; i < 2; ++i) {
        acc[i][j] = __builtin_amdgcn_mfma_f32_16x16x32_f16(ah[i], bh, acc[i][j], 0, 0, 0);
        acc[i][j] = __builtin_amdgcn_mfma_f32_16x16x32_f16(al[i], bh, acc[i][j], 0, 0, 0);
      }
    }
    __syncthreads();
  }

  // bias for this wave's cols
  float bw[5];
#pragma unroll
  for (int j = 0; j < 5; ++j) bw[j] = bias[80 * w + 16 * j + frow];

  // -------- epilogue: two group phases --------
#pragma unroll
  for (int g = 0; g < G_DIM; ++g) {
    __syncthreads();  // staging/prev-phase LDS dead
    if ((w >> 2) == g) {
      const int cg0 = 80 * (w & 3) + frow;
#pragma unroll
      for (int i = 0; i < 2; ++i)
#pragma unroll
        for (int j = 0; j < 5; ++j)
#pragma unroll
          for (int r = 0; r < 4; ++r)
            Ldump[(16 * i + 4 * quad + r) * 321 + cg0 + 16 * j] = acc[i][j][r] + bw[j];
    }
    __syncthreads();

    float pacc5[5] = {0.0f, 0.0f, 0.0f, 0.0f, 0.0f};
#pragma unroll
    for (int rr = 0; rr < 4; ++rr) {
      const int row = w * 4 + rr;
      const int n = m0 + row;
      const float* gp = gn + (size_t)(2 * n + g) * V_DIM;

      float l[5], t[5];
#pragma unroll
      for (int j = 0; j < 5; ++j) {
        l[j] = Ldump[row * 321 + lane + 64 * j];
        t[j] = (l[j] + gp[lane + 64 * j]) * 0.5f;
      }

      // argmax of l (first index on ties)
      float m = l[0]; int mi_ = lane;
#pragma unroll
      for (int j = 1; j < 5; ++j) {
        const int v = lane + 64 * j;
        if (l[j] > m) { m = l[j]; mi_ = v; }
      }
#pragma unroll
      for (int off = 32; off > 0; off >>= 1) {
        const float om = __shfl_xor(m, off, 64);
        const int omi = __shfl_xor(mi_, off, 64);
        if (om > m || (om == m && omi < mi_)) { m = om; mi_ = omi; }
      }
      if (lane == 0) atomicAdd(&cntL[g * V_DIM + mi_], 1);

      // softmax of l
      float e[5], s = 0.0f;
#pragma unroll
      for (int j = 0; j < 5; ++j) { e[j] = expf(l[j] - m); s += e[j]; }
#pragma unroll
      for (int off = 32; off > 0; off >>= 1) s += __shfl_xor(s, off, 64);
      const float inv = 1.0f / s;
#pragma unroll
      for (int j = 0; j < 5; ++j) pacc5[j] += e[j] * inv;

      // gumbel path
      float tm = t[0]; int ti = lane;
#pragma unroll
      for (int j = 1; j < 5; ++j) {
        const int v = lane + 64 * j;
        if (t[j] > tm) { tm = t[j]; ti = v; }
      }
#pragma unroll
      for (int off = 32; off > 0; off >>= 1) {
        const float om = __shfl_xor(tm, off, 64);
        const int omi = __shfl_xor(ti, off, 64);
        if (om > tm || (om == tm && omi < ti)) { tm = om; ti = omi; }
      }
      float ts = 0.0f;
#pragma unroll
      for (int j = 0; j < 5; ++j) ts += expf(t[j] - tm);
#pragma unroll
      for (int off = 32; off > 0; off >>= 1) ts += __shfl_xor(ts, off, 64);
      const float sv = 1.0f / ts;
      const float yv = (1.0f + sv) - sv;  // straight-through value at argmax

      const float4 c4 = ((const float4*)(cb + ((size_t)(g * V_DIM + ti)) * D_DIM))[lane];
      float4 o4;
      o4.x = yv * c4.x; o4.y = yv * c4.y; o4.z = yv * c4.z; o4.w = yv * c4.w;
      ((float4*)q)[(size_t)n * 128 + g * 64 + lane] = o4;
    }
#pragma unroll
    for (int j = 0; j < 5; ++j)
      atomicAdd(&accL[g * V_DIM + lane + 64 * j], pacc5[j]);
  }

  __syncthreads();
  const size_t pb = (size_t)(blockIdx.x & (NBUCKET - 1)) * GV;
  for (int e = tid; e < GV; e += 512) {
    atomicAdd(&mf[pb + e], accL[e]);
    atomicAdd(&mi[pb + e], cntL[e]);
  }
}

// ---------------- Finalize: sum 64 buckets, entropies, outputs ----------------
__global__ __launch_bounds__(256) void finalize_kernel(
    const float* __restrict__ mf, const int* __restrict__ mi,
    float* __restrict__ out3) {
  __shared__ float sA[G_DIM];
  __shared__ float sC[G_DIM];
  if (threadIdx.x < G_DIM) { sA[threadIdx.x] = 0.0f; sC[threadIdx.x] = 0.0f; }
  __syncthreads();

  for (int e = threadIdx.x; e < GV; e += 256) {
    float f = 0.0f; int c = 0;
#pragma unroll
    for (int b = 0; b < NBUCKET; ++b) {
      f += mf[(size_t)b * GV + e];
      c += mi[(size_t)b * GV + e];
    }
    const int g = e / V_DIM;
    const float pa = f * (1.0f / 16384.0f);
    const float ph = (float)c * (1.0f / 16384.0f);
    atomicAdd(&sA[g], pa * logf(pa + 1e-7f));
    atomicAdd(&sC[g], ph * logf(ph + 1e-7f));
  }
  __syncthreads();
  if (threadIdx.x == 0) {
    const float code_p = expf(-sC[0]) + expf(-sC[1]);
    const float prob_p = expf(-sA[0]) + expf(-sA[1]);
    out3[0] = code_p;
    out3[1] = prob_p;
    out3[2] = ((float)GV - prob_p) / (float)GV;
  }
}

extern "C" void kernel_launch(void* const* d_in, const int* in_sizes, int n_in,
                              void* d_out, int out_size, void* d_ws, size_t ws_size,
                              hipStream_t stream) {
  const float* x  = (const float*)d_in[0];  // [8,2048,1024]
  const float* W  = (const float*)d_in[1];  // [640,1024]
  const float* b  = (const float*)d_in[2];  // [640]
  const float* cb = (const float*)d_in[3];  // [1,640,256]
  const float* gn = (const float*)d_in[4];  // [32768,320]
  float* out = (float*)d_out;               // q [16384*512] + 3 scalars

  char* ws = (char*)d_ws;
  _Float16* whT = (_Float16*)ws;             // 1,310,720 B
  float* mf = (float*)(ws + 1310720);        // 64*640*4 = 163,840 B
  int*   mi = (int*)  (ws + 1474560);        // 163,840 B

  hipMemsetAsync(mf, 0, 2 * 163840, stream);

  wsplit_kernel<<<(GV * C_DIM / 8) / 256, 256, 0, stream>>>(W, whT);

  fused_kernel<<<FBLKS, 512, 0, stream>>>(x, whT, b, gn, cb, out, mf, mi);

  finalize_kernel<<<1, 256, 0, stream>>>(mf, mi, out + (size_t)N_ROWS * 512);
}